// Round 6
// baseline (188.260 us; speedup 1.0000x reference)
//
#include <hip/hip_runtime.h>
#include <stdint.h>
#include <math.h>

#pragma clang fp contract(off)

#define N_ROWS 1048576
#define N_CLS  20
#define K_TOP  2000
#define CAND_MAX 4096
#define H_COPIES 4

// scal slots (dwords)
#define SC_CNT   0
#define SC_MAXK  1
#define SC_DONE  2   // maskscan done-counter
#define SC_DONE2 3   // comprank done-counter

// ws layout
static constexpr size_t OFF_MKEY  = 0;                             // u32[N]
static constexpr size_t OFF_CLS   = OFF_MKEY + 4ull * N_ROWS;      // u8[N]
static constexpr size_t OFF_HIST1 = OFF_CLS + (size_t)N_ROWS;      // u32[4*256] -- zero region start
static constexpr size_t OFF_HIST2 = OFF_HIST1 + 4096;              // u32[4*256]
static constexpr size_t OFF_SCAL  = OFF_HIST2 + 4096;              // u32[16]
static constexpr size_t OFF_GRP   = OFF_SCAL + 64;                 // u64[32]    -- zero region end
static constexpr size_t OFF_CAND  = OFF_GRP + 256;                 // u64[CAND_MAX]
static constexpr size_t OFF_MASK  = OFF_CAND + 8ull * CAND_MAX;    // u64[K_TOP*32]
static constexpr int ZERO_DWORDS = H_COPIES * 256 * 2 + 16 + 64;   // 2128

__device__ __forceinline__ uint32_t mono_key(float f) {
    uint32_t u = __float_as_uint(f);
    return u ^ ((u & 0x80000000u) ? 0xFFFFFFFFu : 0x80000000u);
}
__device__ __forceinline__ float mono_inv(uint32_t k) {
    uint32_t u = (k & 0x80000000u) ? (k ^ 0x80000000u) : ~k;
    return __uint_as_float(u);
}

// ---- D1: per-row max/argmax of logits (LDS-staged coalesced loads) -> mkey, cls.
//      Also zeroes hist1/hist2/scal/grp (first written in later dispatches -> no race).
__global__ __launch_bounds__(256) void k_score(const float* __restrict__ logits,
                                               uint32_t* __restrict__ mkey,
                                               uint8_t* __restrict__ cls,
                                               uint32_t* __restrict__ zreg) {
    __shared__ uint32_t stage[256 * 21];   // 256 rows x 20 words, padded to 21
    int t = threadIdx.x;
    if (t < 4) {
        int zi = blockIdx.x * 4 + t;
        if (zi < ZERO_DWORDS) zreg[zi] = 0;
    }
    int waddr[20];
#pragma unroll
    for (int q = 0; q < 5; ++q) {
#pragma unroll
        for (int e = 0; e < 4; ++e) {
            int w = (q * 256 + t) * 4 + e;
            int r = w / 20, c = w - r * 20;
            waddr[q * 4 + e] = r * 21 + c;
        }
    }
    size_t blockRowBase = (size_t)blockIdx.x * 1024;
    for (int g = 0; g < 4; ++g) {
        const float4* src = (const float4*)(logits + (blockRowBase + (size_t)g * 256) * N_CLS);
#pragma unroll
        for (int q = 0; q < 5; ++q) {
            float4 v = src[q * 256 + t];            // fully coalesced 16B/lane
            stage[waddr[q * 4 + 0]] = __float_as_uint(v.x);
            stage[waddr[q * 4 + 1]] = __float_as_uint(v.y);
            stage[waddr[q * 4 + 2]] = __float_as_uint(v.z);
            stage[waddr[q * 4 + 3]] = __float_as_uint(v.w);
        }
        __syncthreads();
        const uint32_t* row = &stage[t * 21];
        float m = __uint_as_float(row[0]); int ci = 0;
#pragma unroll
        for (int c = 1; c < 20; ++c) {
            float v = __uint_as_float(row[c]);
            if (v > m) { m = v; ci = c; }
        }
        size_t rowIdx = blockRowBase + (size_t)g * 256 + t;
        mkey[rowIdx] = mono_key(m);
        cls[rowIdx] = (uint8_t)ci;
        __syncthreads();
    }
}

// ---- D2: global 256-bin top-byte histogram (LDS pre-agg, 4 spread copies)
__global__ __launch_bounds__(256) void k_hist1(const uint32_t* __restrict__ mkey,
                                               uint32_t* __restrict__ hist1) {
    __shared__ uint32_t h[256];
    int t = threadIdx.x;
    h[t] = 0;
    __syncthreads();
    const uint4* m4 = (const uint4*)mkey;
    size_t base = (size_t)blockIdx.x * 1024;
    for (int it = 0; it < 4; ++it) {
        uint4 v = m4[base + it * 256 + t];
        atomicAdd(&h[v.x >> 24], 1u);
        atomicAdd(&h[v.y >> 24], 1u);
        atomicAdd(&h[v.z >> 24], 1u);
        atomicAdd(&h[v.w >> 24], 1u);
    }
    __syncthreads();
    uint32_t hv = h[t];
    if (hv) atomicAdd(&hist1[(blockIdx.x & (H_COPIES - 1)) * 256 + t], hv);
}

// find8: suffix scan over summed hist1 -> (b0, R1). Runs redundantly per block.
// Works for any blockDim >= 256 (threads >= 256 idle through barriers).
__device__ __forceinline__ void find8(const uint32_t* __restrict__ hist1,
                                      uint32_t* sfx, uint32_t* pb0, uint32_t* pR1,
                                      uint32_t& b0, uint32_t& R1) {
    int t = threadIdx.x;
    uint32_t h = 0;
    if (t < 256) {
#pragma unroll
        for (int k = 0; k < H_COPIES; ++k) h += hist1[k * 256 + t];
        sfx[t] = h;
    }
    __syncthreads();
    for (int off = 1; off < 256; off <<= 1) {
        uint32_t v = (t < 256 && t + off < 256) ? sfx[t + off] : 0;
        __syncthreads();
        if (t < 256) sfx[t] += v;
        __syncthreads();
    }
    if (t < 256 && sfx[t] >= (uint32_t)K_TOP && (t == 255 || sfx[t + 1] < (uint32_t)K_TOP)) {
        *pb0 = (uint32_t)t;
        *pR1 = (uint32_t)K_TOP - (sfx[t] - h);
    }
    __syncthreads();
    b0 = *pb0; R1 = *pR1;
}

// ---- D3: restricted 8-bit stage-2 histogram (bits 23:16 where top byte == b0)
__global__ __launch_bounds__(256) void k_hist2(const uint32_t* __restrict__ mkey,
                                               const uint32_t* __restrict__ hist1,
                                               uint32_t* __restrict__ hist2) {
    __shared__ uint32_t sfx[256];
    __shared__ uint32_t h2[256];
    __shared__ uint32_t sb0, sR1;
    int t = threadIdx.x;
    h2[t] = 0;
    uint32_t b0, R1;
    find8(hist1, sfx, &sb0, &sR1, b0, R1);
    uint4 v = ((const uint4*)mkey)[(size_t)blockIdx.x * 256 + t];  // 1024 rows/block
    if ((v.x >> 24) == b0) atomicAdd(&h2[(v.x >> 16) & 0xFFu], 1u);
    if ((v.y >> 24) == b0) atomicAdd(&h2[(v.y >> 16) & 0xFFu], 1u);
    if ((v.z >> 24) == b0) atomicAdd(&h2[(v.z >> 16) & 0xFFu], 1u);
    if ((v.w >> 24) == b0) atomicAdd(&h2[(v.w >> 16) & 0xFFu], 1u);
    __syncthreads();
    uint32_t hv = h2[t];
    if (hv) atomicAdd(&hist2[(blockIdx.x & (H_COPIES - 1)) * 256 + t], hv);
}

// ---- D4: per-block redundant final find (find8 + stage-2 suffix scan -> T16-1),
//      compact candidates ((mkey>>16) >= T) via atomicExch into cand, then
//      atomic-only last-block handoff -> rank-by-counting + decode + out writes.
__global__ __launch_bounds__(1024) void k_comprank(const uint32_t* __restrict__ mkey,
                                                   const uint32_t* __restrict__ hist1,
                                                   const uint32_t* __restrict__ hist2,
                                                   uint32_t* __restrict__ scal,
                                                   unsigned long long* __restrict__ cand,
                                                   const float* __restrict__ deltas,
                                                   const float* __restrict__ locs,
                                                   const int* __restrict__ stridep,
                                                   const uint8_t* __restrict__ cls,
                                                   float* __restrict__ out) {
    __shared__ uint32_t sfx[256];
    __shared__ uint32_t sb0, sR1, sT;
    __shared__ uint32_t cnt, gbase;
    __shared__ uint64_t stg[1024];
    __shared__ uint64_t keys[CAND_MAX];   // used only by the last block (rank phase)
    __shared__ float red[16];
    __shared__ int lastdone;
    int t = threadIdx.x;
    int lane = t & 63;
    if (t == 0) cnt = 0;
    uint32_t b0, R1;
    find8(hist1, sfx, &sb0, &sR1, b0, R1);
    // stage-2 suffix scan (reuse sfx; everyone past the barrier inside find8)
    uint32_t h = 0;
    if (t < 256) {
#pragma unroll
        for (int k = 0; k < H_COPIES; ++k) h += hist2[k * 256 + t];
        sfx[t] = h;
    }
    __syncthreads();
    for (int off = 1; off < 256; off <<= 1) {
        uint32_t v = (t < 256 && t + off < 256) ? sfx[t + off] : 0;
        __syncthreads();
        if (t < 256) sfx[t] += v;
        __syncthreads();
    }
    if (t < 256 && sfx[t] >= R1 && (t == 255 || sfx[t + 1] < R1)) {
        uint32_t t16 = (b0 << 8) | (uint32_t)t;
        sT = (t16 > 0) ? (t16 - 1) : 0;            // -1 bin safety: rounded-sigmoid ties
    }
    __syncthreads();
    uint32_t T = sT;

    // compact: 16384 rows per block (4096 uint4 / 1024 threads / 4 iters)
    const uint4* m4 = (const uint4*)mkey;
    size_t base = (size_t)blockIdx.x * 4096;       // uint4 units
    for (int it = 0; it < 4; ++it) {
        size_t i4 = base + (size_t)it * 1024 + t;
        uint32_t r0 = (uint32_t)(i4 * 4);
        uint4 v = m4[i4];
#pragma unroll
        for (int e = 0; e < 4; ++e) {
            uint32_t u = (e == 0) ? v.x : (e == 1) ? v.y : (e == 2) ? v.z : v.w;
            bool pass = (u >> 16) >= T;
            unsigned long long bal = __ballot(pass);
            if (bal) {
                uint32_t wbase = 0;
                if (lane == 0) wbase = atomicAdd(&cnt, (uint32_t)__popcll(bal));
                wbase = __shfl(wbase, 0);
                if (pass) {
                    uint32_t pos = wbase + (uint32_t)__popcll(bal & ((1ull << lane) - 1ull));
                    if (pos < 1024) stg[pos] = ((uint64_t)u << 32) | (r0 + e);
                }
            }
        }
    }
    __syncthreads();
    uint32_t n = cnt; if (n > 1024) n = 1024;
    if (t == 0 && n) gbase = atomicAdd(&scal[SC_CNT], n);
    __syncthreads();
    unsigned long long dummy = 0;
    if (n) {
        uint32_t gb = gbase;
        for (uint32_t i = t; i < n; i += 1024) {
            uint32_t pos = gb + i;
            if (pos < (uint32_t)CAND_MAX)
                dummy += atomicExch(&cand[pos], (unsigned long long)stg[i]);  // device-coherent
        }
    }
    asm volatile("" :: "v"(dummy));                 // force atomic returns
    asm volatile("s_waitcnt vmcnt(0) lgkmcnt(0)" ::: "memory");
    __syncthreads();
    if (t == 0) {
        unsigned old = atomicAdd(&scal[SC_DONE2], 1u);
        lastdone = (old == (unsigned)(gridDim.x - 1)) ? 1 : 0;
    }
    __syncthreads();
    if (!lastdone) return;

    // ---- rank phase (last block only, 1024 threads) ----
    uint32_t M = atomicAdd(&scal[SC_CNT], 0u);
    if (M > (uint32_t)CAND_MAX) M = CAND_MAX;
    for (uint32_t i = t; i < M; i += 1024) {
        unsigned long long cd = atomicOr(&cand[i], 0ull);   // coherent fetch
        uint32_t mk = (uint32_t)(cd >> 32);
        uint32_t row = (uint32_t)cd & (N_ROWS - 1);
        float m = mono_inv(mk);
        float ef = (float)exp(-(double)m);          // ~correctly-rounded fp32 expf
        float s = 1.0f / (1.0f + ef);
        keys[i] = ((uint64_t)(~__float_as_uint(s)) << 32) | row;
    }
    __syncthreads();
    float mx = -3.4e38f;
    float stridef = (float)(*stridep);
    for (uint32_t c = t; c < M; c += 1024) {
        uint64_t my = keys[c];
        uint32_t rank = 0;
        uint32_t j = 0;
        for (; j + 4 <= M; j += 4) {                // uniform-address LDS reads -> broadcast
            ulonglong2 a = *(const ulonglong2*)&keys[j];
            ulonglong2 b = *(const ulonglong2*)&keys[j + 2];
            rank += (a.x < my) + (a.y < my) + (b.x < my) + (b.y < my);
        }
        for (; j < M; ++j) rank += (keys[j] < my);
        if (rank < (uint32_t)K_TOP) {
            uint32_t row = (uint32_t)my & (N_ROWS - 1);
            float s = __uint_as_float(~(uint32_t)(my >> 32));
            float4 dl = ((const float4*)deltas)[row];
            float2 lc = ((const float2*)locs)[row];
            float d0 = dl.x * stridef, d1 = dl.y * stridef, d2 = dl.z * stridef, d3 = dl.w * stridef;
            float b0f = lc.x - d0, b1f = lc.y - d1, b2f = lc.x + d2, b3f = lc.y + d3;
            float4 bx = { b0f, b1f, b2f, b3f };
            *(float4*)&out[4 * rank] = bx;
            out[8000 + rank] = s;
            out[10000 + rank] = (float)cls[row];
            mx = fmaxf(mx, fmaxf(fmaxf(b0f, b1f), fmaxf(b2f, b3f)));
        }
    }
    for (int o = 32; o > 0; o >>= 1) mx = fmaxf(mx, __shfl_down(mx, o));
    if ((t & 63) == 0) red[t >> 6] = mx;
    __syncthreads();
    if (t == 0) {
        float m2 = red[0];
        for (int i = 1; i < 16; ++i) m2 = fmaxf(m2, red[i]);
        scal[SC_MAXK] = mono_key(m2);               // visible next dispatch (boundary flush)
    }
}

// ---- D5: pairwise suppression mask (quirky IoU replicated exactly) + fused scan.
//      Atomic-only cross-block handoff (proven in R5): atomicExch payload, consume
//      returns + s_waitcnt (cheap wave drain, NOT a cache flush), done-counter;
//      last block scans via atomic fetches. 500 blocks, wave = one i-row.
__global__ __launch_bounds__(256) void k_maskscan(const float* __restrict__ out_ro,
                                                  uint32_t* __restrict__ scal,
                                                  uint64_t* __restrict__ mask,
                                                  unsigned long long* __restrict__ grp,
                                                  float* __restrict__ out) {
    __shared__ int lastdone;
    int t = threadIdx.x;
    int lane = t & 63;
    int i = blockIdx.x * 4 + (t >> 6);              // 2000 waves total
    float off1 = mono_inv(scal[SC_MAXK]) + 1.0f;    // max_coord + 1 (prev dispatch, coherent)
    float4 boxi = *(const float4*)&out_ro[4 * i];
    float oi = out_ro[10000 + i] * off1;
    float x1i = boxi.x + oi, y2i = boxi.y + oi, x2i = boxi.z + oi, y1i = boxi.w + oi;
    float ai = (x2i - x1i) * (y2i - y1i);
    unsigned long long dummy = 0;
    for (int jb = 0; jb < 32; ++jb) {
        int j = jb * 64 + lane;
        bool sup = false;
        if (j < K_TOP && j > i) {
            float4 boxj = *(const float4*)&out_ro[4 * j];
            float oj = out_ro[10000 + j] * off1;
            float x1j = boxj.x + oj, y2j = boxj.y + oj, x2j = boxj.z + oj, y1j = boxj.w + oj;
            float aj = (x2j - x1j) * (y2j - y1j);
            float xx1 = fmaxf(x1i, x1j);
            float yy1 = fminf(y1i, y1j);
            float xx2 = fminf(x2i, x2j);
            float yy2 = fmaxf(y2i, y2j);
            float inter = fabsf(xx2 - xx1) * fabsf(yy2 - yy1);
            float iou = inter / ((ai + aj) - inter);
            sup = iou > 0.5f;
        }
        unsigned long long bits = __ballot(sup);
        if (lane == 0) {
            dummy += atomicExch(&mask[(size_t)i * 32 + jb], bits);
            if (bits) dummy += atomicOr(&grp[i >> 6], 1ull << (i & 63));
        }
    }
    asm volatile("" :: "v"(dummy));                 // force atomic returns (vmcnt drained)
    asm volatile("s_waitcnt vmcnt(0) lgkmcnt(0)" ::: "memory");
    __syncthreads();
    if (t == 0) {
        unsigned old = atomicAdd(&scal[SC_DONE], 1u);
        lastdone = (old == (unsigned)(gridDim.x - 1)) ? 1 : 0;
    }
    __syncthreads();
    if (!lastdone) return;

    if (t < 64) {
        int l = t;                                  // lane w<32 holds active word w
        uint64_t g = (l < 32) ? atomicOr(&grp[l], 0ull) : 0ull;
        uint64_t active = ~0ull;
        if (__ballot(g != 0ull)) {
            for (int gg = 0; gg < 32; ++gg) {
                uint64_t nz = __shfl(g, gg);
                while (nz) {
                    int b = __ffsll((long long)nz) - 1;
                    nz &= nz - 1;
                    int ii = gg * 64 + b;
                    uint64_t aw = __shfl(active, gg);
                    bool kept = (aw >> b) & 1ull;
                    uint64_t m = (l < 32) ? atomicOr(&mask[(size_t)ii * 32 + l], 0ull) : 0ull;
                    if (kept) active &= ~m;
                }
            }
        }
        if (l < 32) {
            int limit = K_TOP - l * 64;
            int nvec = limit < 64 ? limit / 4 : 16;
            for (int v = 0; v < nvec; ++v) {
                float4 f;
                f.x = ((active >> (4 * v + 0)) & 1ull) ? 1.0f : 0.0f;
                f.y = ((active >> (4 * v + 1)) & 1ull) ? 1.0f : 0.0f;
                f.z = ((active >> (4 * v + 2)) & 1ull) ? 1.0f : 0.0f;
                f.w = ((active >> (4 * v + 3)) & 1ull) ? 1.0f : 0.0f;
                *(float4*)&out[12000 + l * 64 + 4 * v] = f;
            }
        }
    }
}

extern "C" void kernel_launch(void* const* d_in, const int* in_sizes, int n_in,
                              void* d_out, int out_size, void* d_ws, size_t ws_size,
                              hipStream_t stream) {
    const float* deltas = (const float*)d_in[0];
    const float* locs   = (const float*)d_in[1];
    const float* logits = (const float*)d_in[2];
    const int*   stridep = (const int*)d_in[3];
    float* out = (float*)d_out;
    char* ws = (char*)d_ws;

    uint32_t* mkey  = (uint32_t*)(ws + OFF_MKEY);
    uint8_t*  cls   = (uint8_t*)(ws + OFF_CLS);
    uint32_t* hist1 = (uint32_t*)(ws + OFF_HIST1);
    uint32_t* hist2 = (uint32_t*)(ws + OFF_HIST2);
    uint32_t* scal  = (uint32_t*)(ws + OFF_SCAL);
    unsigned long long* grp = (unsigned long long*)(ws + OFF_GRP);
    unsigned long long* cand = (unsigned long long*)(ws + OFF_CAND);
    uint64_t* mask  = (uint64_t*)(ws + OFF_MASK);

    k_score<<<dim3(1024), dim3(256), 0, stream>>>(logits, mkey, cls, hist1);
    k_hist1<<<dim3(256), dim3(256), 0, stream>>>(mkey, hist1);
    k_hist2<<<dim3(1024), dim3(256), 0, stream>>>(mkey, hist1, hist2);
    k_comprank<<<dim3(64), dim3(1024), 0, stream>>>(mkey, hist1, hist2, scal, cand,
                                                    deltas, locs, stridep, cls, out);
    k_maskscan<<<dim3(500), dim3(256), 0, stream>>>(out, scal, mask, grp, out);
}

// Round 7
// 97.902 us; speedup vs baseline: 1.9230x; 1.9230x over previous
//
#include <hip/hip_runtime.h>
#include <stdint.h>
#include <math.h>

#pragma clang fp contract(off)

#define N_ROWS 1048576
#define N_CLS  20
#define K_TOP  2000
#define CAND_MAX 4096
#define H_COPIES 4
#define MAGIC 0x5AD0C0DEu
#define NBLK_SCORE 512

// scal slots (dwords) -- all inside the zeroed region
#define SC_CNT   0
#define SC_MAXK  1
#define SC_DONE  2   // maskscan done-counter
#define SC_BAR   3   // k_score grid-barrier arrival counter
#define SC_FLAG  4   // k_score grid-barrier release flag

// ws layout
static constexpr size_t OFF_MKEY  = 0;                             // u32[N]
static constexpr size_t OFF_CLS   = OFF_MKEY + 4ull * N_ROWS;      // u8[N]
static constexpr size_t OFF_HIST1 = OFF_CLS + (size_t)N_ROWS;      // u32[4*256] -- zero region start
static constexpr size_t OFF_HIST2 = OFF_HIST1 + 4096;              // u32[4*256]
static constexpr size_t OFF_SCAL  = OFF_HIST2 + 4096;              // u32[16]
static constexpr size_t OFF_GRP   = OFF_SCAL + 64;                 // u64[32]    -- zero region end (2128 dwords)
static constexpr size_t OFF_ZIN   = OFF_GRP + 256;                 // u32[8] MAGIC words (reset by D4, garbage-proof)
static constexpr size_t OFF_CAND  = OFF_ZIN + 256;                 // u64[CAND_MAX]
static constexpr size_t OFF_MASK  = OFF_CAND + 8ull * CAND_MAX;    // u64[K_TOP*32]

__device__ __forceinline__ uint32_t mono_key(float f) {
    uint32_t u = __float_as_uint(f);
    return u ^ ((u & 0x80000000u) ? 0xFFFFFFFFu : 0x80000000u);
}
__device__ __forceinline__ float mono_inv(uint32_t k) {
    uint32_t u = (k & 0x80000000u) ? (k ^ 0x80000000u) : ~k;
    return __uint_as_float(u);
}

// ---- D1: score (max/argmax via LDS-staged coalesced loads) + BOTH histogram stages,
//      joined by an atomic-only in-kernel grid barrier (512 blocks, co-resident by
//      capacity: <=2 blocks/CU needed, >=4 available). No threadfence anywhere.
__global__ __launch_bounds__(256, 4) void k_score(const float* __restrict__ logits,
                                                  uint32_t* __restrict__ mkey,
                                                  uint8_t* __restrict__ cls,
                                                  uint32_t* __restrict__ hist1,   // zero region base
                                                  uint32_t* __restrict__ hist2,
                                                  uint32_t* __restrict__ scal,
                                                  uint32_t* __restrict__ zin) {
    __shared__ uint32_t stage[256 * 21];
    __shared__ uint32_t h1[256];
    __shared__ uint32_t sfx[256];
    __shared__ uint32_t sb0;
    int t = threadIdx.x, b = blockIdx.x;

    // zero phase: blocks 0..7 zero the 2128-dword region via device atomics,
    // then publish MAGIC (value-semantic: immune to poison/garbage init).
    if (b < 8) {
        uint32_t zd = atomicExch(&hist1[b * 256 + t], 0u);
        if (b == 7 && t < 80) zd += atomicExch(&hist1[2048 + t], 0u);
        asm volatile("" :: "v"(zd));
        asm volatile("s_waitcnt vmcnt(0)" ::: "memory");
        __syncthreads();
        if (t == 0) atomicExch(&zin[b], MAGIC);
    }

    h1[t] = 0;
    __syncthreads();
    size_t rowbase0 = (size_t)b * 2048;
    for (int g = 0; g < 8; ++g) {
        const float4* src = (const float4*)(logits + (rowbase0 + (size_t)g * 256) * N_CLS);
#pragma unroll
        for (int q = 0; q < 5; ++q) {
            float4 v = src[q * 256 + t];            // fully coalesced 16B/lane
            int w0 = (q * 256 + t) * 4;
#pragma unroll
            for (int e = 0; e < 4; ++e) {
                int w = w0 + e;                     // stage addr = w + w/20  (row pad 20->21)
                stage[w + ((w * 52429u) >> 20)] = __float_as_uint((&v.x)[e]);
            }
        }
        __syncthreads();
        const uint32_t* row = &stage[t * 21];
        float m = __uint_as_float(row[0]); int ci = 0;
#pragma unroll
        for (int c = 1; c < 20; ++c) {
            float v = __uint_as_float(row[c]);
            if (v > m) { m = v; ci = c; }
        }
        size_t ri = rowbase0 + (size_t)g * 256 + t;
        uint32_t u = mono_key(m);
        mkey[ri] = u;
        cls[ri] = (uint8_t)ci;
        atomicAdd(&h1[u >> 24], 1u);
        __syncthreads();
    }

    // spin-(i): wait zeroing done (typically instant: zero ~1us << compute ~13us)
    for (;;) {
        int ok = 1;
        if (t < 8) ok = (atomicAdd(&zin[t], 0u) == MAGIC) ? 1 : 0;
        if (__syncthreads_count(ok) == 256) break;
        __builtin_amdgcn_s_sleep(16);
    }

    // stage-1 global adds (4 spread copies), drained before arrival
    uint32_t hv = h1[t], dm = 0;
    if (hv) dm = atomicAdd(&hist1[(b & 3) * 256 + t], hv);
    asm volatile("" :: "v"(dm));
    asm volatile("s_waitcnt vmcnt(0)" ::: "memory");
    __syncthreads();
    if (t == 0) {
        uint32_t old = atomicAdd(&scal[SC_BAR], 1u);          // counter lives in zeroed region
        if (old == (uint32_t)(NBLK_SCORE - 1)) atomicExch(&scal[SC_FLAG], MAGIC);
    }
    // grid barrier release: 1 poller/block on a single flag line, s_sleep backoff
    for (;;) {
        int ok = 1;
        if (t == 0) ok = (atomicAdd(&scal[SC_FLAG], 0u) == MAGIC) ? 1 : 0;
        if (__syncthreads_count(ok) == 256) break;
        __builtin_amdgcn_s_sleep(64);
    }

    // find b0 (redundant per block) from completed hist1, atomic fetches
    uint32_t hh = 0;
#pragma unroll
    for (int k = 0; k < H_COPIES; ++k) hh += atomicAdd(&hist1[k * 256 + t], 0u);
    sfx[t] = hh;
    __syncthreads();
    for (int off = 1; off < 256; off <<= 1) {
        uint32_t v = (t + off < 256) ? sfx[t + off] : 0;
        __syncthreads();
        sfx[t] += v;
        __syncthreads();
    }
    if (sfx[t] >= (uint32_t)K_TOP && (t == 255 || sfx[t + 1] < (uint32_t)K_TOP)) sb0 = (uint32_t)t;
    __syncthreads();
    uint32_t b0 = sb0;

    // stage-2 restricted histogram (re-read own mkey rows: same-XCD, coherent)
    h1[t] = 0;
    __syncthreads();
    for (int g = 0; g < 8; ++g) {
        uint32_t u = mkey[rowbase0 + (size_t)g * 256 + t];
        if ((u >> 24) == b0) atomicAdd(&h1[(u >> 16) & 0xFFu], 1u);
    }
    __syncthreads();
    hv = h1[t];
    if (hv) atomicAdd(&hist2[(b & 3) * 256 + t], hv);   // kernel-end drain handles visibility
}

// find8: suffix scan over summed hist1 -> (b0, R1). Runs redundantly per block (plain
// loads: cross-dispatch coherent).
__device__ __forceinline__ void find8(const uint32_t* __restrict__ hist1,
                                      uint32_t* sfx, uint32_t* pb0, uint32_t* pR1,
                                      uint32_t& b0, uint32_t& R1) {
    int t = threadIdx.x;
    uint32_t h = 0;
#pragma unroll
    for (int k = 0; k < H_COPIES; ++k) h += hist1[k * 256 + t];
    sfx[t] = h;
    __syncthreads();
    for (int off = 1; off < 256; off <<= 1) {
        uint32_t v = (t + off < 256) ? sfx[t + off] : 0;
        __syncthreads();
        sfx[t] += v;
        __syncthreads();
    }
    if (sfx[t] >= (uint32_t)K_TOP && (t == 255 || sfx[t + 1] < (uint32_t)K_TOP)) {
        *pb0 = (uint32_t)t;
        *pR1 = (uint32_t)K_TOP - (sfx[t] - h);
    }
    __syncthreads();
    b0 = *pb0; R1 = *pR1;
}

// ---- D2: per-block redundant final find (find8 + stage-2 suffix scan -> T16-1),
//      then compact candidates ((mkey>>16) >= T), LDS-staged, 1 global atomic/block.
__global__ __launch_bounds__(256) void k_compact(const uint32_t* __restrict__ mkey,
                                                 const uint32_t* __restrict__ hist1,
                                                 const uint32_t* __restrict__ hist2,
                                                 uint32_t* __restrict__ scal,
                                                 unsigned long long* __restrict__ cand) {
    __shared__ uint32_t sfx[256];
    __shared__ uint32_t sb0, sR1, sT;
    __shared__ uint32_t cnt, gbase;
    __shared__ uint64_t stg[1024];
    int t = threadIdx.x;
    int lane = t & 63;
    if (t == 0) cnt = 0;
    uint32_t b0, R1;
    find8(hist1, sfx, &sb0, &sR1, b0, R1);
    // stage-2 suffix scan (reuse sfx)
    uint32_t h = 0;
#pragma unroll
    for (int k = 0; k < H_COPIES; ++k) h += hist2[k * 256 + t];
    __syncthreads();
    sfx[t] = h;
    __syncthreads();
    for (int off = 1; off < 256; off <<= 1) {
        uint32_t v = (t + off < 256) ? sfx[t + off] : 0;
        __syncthreads();
        sfx[t] += v;
        __syncthreads();
    }
    if (sfx[t] >= R1 && (t == 255 || sfx[t + 1] < R1)) {
        uint32_t t16 = (b0 << 8) | (uint32_t)t;
        sT = (t16 > 0) ? (t16 - 1) : 0;            // -1 bin safety: rounded-sigmoid ties
    }
    __syncthreads();
    uint32_t T = sT;
    const uint4* m4 = (const uint4*)mkey;
    size_t base = (size_t)blockIdx.x * 1024;       // uint4 index; 4096 rows/block
    for (int it = 0; it < 4; ++it) {
        uint32_t r0 = (uint32_t)((base + it * 256 + t) * 4);
        uint4 v = m4[base + it * 256 + t];
#pragma unroll
        for (int e = 0; e < 4; ++e) {
            uint32_t u = (e == 0) ? v.x : (e == 1) ? v.y : (e == 2) ? v.z : v.w;
            bool pass = (u >> 16) >= T;
            unsigned long long bal = __ballot(pass);
            if (bal) {
                uint32_t wbase = 0;
                if (lane == 0) wbase = atomicAdd(&cnt, (uint32_t)__popcll(bal));
                wbase = __shfl(wbase, 0);
                if (pass) {
                    uint32_t pos = wbase + (uint32_t)__popcll(bal & ((1ull << lane) - 1ull));
                    if (pos < 1024) stg[pos] = ((uint64_t)u << 32) | (r0 + e);
                }
            }
        }
    }
    __syncthreads();
    uint32_t n = cnt; if (n > 1024) n = 1024;
    if (t == 0 && n) gbase = atomicAdd(&scal[SC_CNT], n);
    __syncthreads();
    if (n) {
        uint32_t gb = gbase;
        for (uint32_t i = t; i < n; i += 256) {
            uint32_t pos = gb + i;
            if (pos < (uint32_t)CAND_MAX) cand[pos] = stg[i];
        }
    }
}

// ---- D3: rank-by-counting, j-PARALLEL: wave-per-candidate, lanes split the scan,
//      shuffle-reduce. O(M^2 / total-lanes) instead of O(M^2 / 64) per wave.
__global__ __launch_bounds__(256) void k_rank(const unsigned long long* __restrict__ cand,
                                              uint32_t* __restrict__ scal,
                                              const float* __restrict__ deltas,
                                              const float* __restrict__ locs,
                                              const int* __restrict__ stridep,
                                              const uint8_t* __restrict__ cls,
                                              float* __restrict__ out) {
    __shared__ uint64_t keys[CAND_MAX];
    int t = threadIdx.x;
    uint32_t M = scal[SC_CNT];
    if (M > (uint32_t)CAND_MAX) M = CAND_MAX;
    for (uint32_t i = t; i < M; i += 256) {
        unsigned long long cd = cand[i];
        uint32_t mk = (uint32_t)(cd >> 32);
        uint32_t row = (uint32_t)cd & (N_ROWS - 1);
        float m = mono_inv(mk);
        float ef = (float)exp(-(double)m);          // ~correctly-rounded fp32 expf
        float s = 1.0f / (1.0f + ef);
        keys[i] = ((uint64_t)(~__float_as_uint(s)) << 32) | row;
    }
    __syncthreads();
    int wid = t >> 6, lane = t & 63;
    float stridef = (float)(*stridep);
    float wmx = -3.4e38f;
    for (uint32_t c = (uint32_t)blockIdx.x * 4 + wid; c < M; c += 256) {  // 64 blocks * 4 waves
        uint64_t myk = keys[c];
        uint32_t r = 0;
        for (uint32_t j = lane; j < M; j += 64) r += (keys[j] < myk) ? 1u : 0u;
#pragma unroll
        for (int o = 32; o > 0; o >>= 1) r += __shfl_down(r, o);
        if (lane == 0 && r < (uint32_t)K_TOP) {
            uint32_t row = (uint32_t)myk & (N_ROWS - 1);
            float s = __uint_as_float(~(uint32_t)(myk >> 32));
            float4 dl = ((const float4*)deltas)[row];
            float2 lc = ((const float2*)locs)[row];
            float d0 = dl.x * stridef, d1 = dl.y * stridef, d2 = dl.z * stridef, d3 = dl.w * stridef;
            float b0f = lc.x - d0, b1f = lc.y - d1, b2f = lc.x + d2, b3f = lc.y + d3;
            float4 bx = { b0f, b1f, b2f, b3f };
            *(float4*)&out[4 * r] = bx;
            out[8000 + r] = s;
            out[10000 + r] = (float)cls[row];
            wmx = fmaxf(wmx, fmaxf(fmaxf(b0f, b1f), fmaxf(b2f, b3f)));
        }
    }
    if (lane == 0) atomicMax(&scal[SC_MAXK], mono_key(wmx));
}

// ---- D4: pairwise suppression mask (quirky IoU replicated exactly) + fused scan.
//      Atomic-only cross-block handoff (proven R5). Tail: reset zin MAGIC words.
__global__ __launch_bounds__(256) void k_maskscan(const float* __restrict__ out_ro,
                                                  uint32_t* __restrict__ scal,
                                                  uint64_t* __restrict__ mask,
                                                  unsigned long long* __restrict__ grp,
                                                  uint32_t* __restrict__ zin,
                                                  float* __restrict__ out) {
    __shared__ int lastdone;
    int t = threadIdx.x;
    int lane = t & 63;
    int i = blockIdx.x * 4 + (t >> 6);              // 2000 waves total
    float off1 = mono_inv(scal[SC_MAXK]) + 1.0f;    // max_coord + 1 (prev dispatch, coherent)
    float4 boxi = *(const float4*)&out_ro[4 * i];
    float oi = out_ro[10000 + i] * off1;
    float x1i = boxi.x + oi, y2i = boxi.y + oi, x2i = boxi.z + oi, y1i = boxi.w + oi;
    float ai = (x2i - x1i) * (y2i - y1i);
    unsigned long long dummy = 0;
    for (int jb = 0; jb < 32; ++jb) {
        int j = jb * 64 + lane;
        bool sup = false;
        if (j < K_TOP && j > i) {
            float4 boxj = *(const float4*)&out_ro[4 * j];
            float oj = out_ro[10000 + j] * off1;
            float x1j = boxj.x + oj, y2j = boxj.y + oj, x2j = boxj.z + oj, y1j = boxj.w + oj;
            float aj = (x2j - x1j) * (y2j - y1j);
            float xx1 = fmaxf(x1i, x1j);
            float yy1 = fminf(y1i, y1j);
            float xx2 = fminf(x2i, x2j);
            float yy2 = fmaxf(y2i, y2j);
            float inter = fabsf(xx2 - xx1) * fabsf(yy2 - yy1);
            float iou = inter / ((ai + aj) - inter);
            sup = iou > 0.5f;
        }
        unsigned long long bits = __ballot(sup);
        if (lane == 0) {
            dummy += atomicExch(&mask[(size_t)i * 32 + jb], bits);
            if (bits) dummy += atomicOr(&grp[i >> 6], 1ull << (i & 63));
        }
    }
    asm volatile("" :: "v"(dummy));                 // force atomic returns (vmcnt drained)
    asm volatile("s_waitcnt vmcnt(0) lgkmcnt(0)" ::: "memory");
    __syncthreads();
    if (t == 0) {
        unsigned old = atomicAdd(&scal[SC_DONE], 1u);
        lastdone = (old == (unsigned)(gridDim.x - 1)) ? 1 : 0;
    }
    __syncthreads();
    if (!lastdone) return;

    if (t < 64) {
        int l = t;                                  // lane w<32 holds active word w
        uint64_t g = (l < 32) ? atomicOr(&grp[l], 0ull) : 0ull;
        uint64_t active = ~0ull;
        if (__ballot(g != 0ull)) {
            for (int gg = 0; gg < 32; ++gg) {
                uint64_t nz = __shfl(g, gg);
                while (nz) {
                    int b = __ffsll((long long)nz) - 1;
                    nz &= nz - 1;
                    int ii = gg * 64 + b;
                    uint64_t aw = __shfl(active, gg);
                    bool kept = (aw >> b) & 1ull;
                    uint64_t m = (l < 32) ? atomicOr(&mask[(size_t)ii * 32 + l], 0ull) : 0ull;
                    if (kept) active &= ~m;
                }
            }
        }
        if (l < 32) {
            int limit = K_TOP - l * 64;
            int nvec = limit < 64 ? limit / 4 : 16;
            for (int v = 0; v < nvec; ++v) {
                float4 f;
                f.x = ((active >> (4 * v + 0)) & 1ull) ? 1.0f : 0.0f;
                f.y = ((active >> (4 * v + 1)) & 1ull) ? 1.0f : 0.0f;
                f.z = ((active >> (4 * v + 2)) & 1ull) ? 1.0f : 0.0f;
                f.w = ((active >> (4 * v + 3)) & 1ull) ? 1.0f : 0.0f;
                *(float4*)&out[12000 + l * 64 + 4 * v] = f;
            }
        }
    }
    // reset MAGIC words for the next replay (zeroed state is what D1 expects)
    if (t < 8) atomicExch(&zin[t], 0u);
}

extern "C" void kernel_launch(void* const* d_in, const int* in_sizes, int n_in,
                              void* d_out, int out_size, void* d_ws, size_t ws_size,
                              hipStream_t stream) {
    const float* deltas = (const float*)d_in[0];
    const float* locs   = (const float*)d_in[1];
    const float* logits = (const float*)d_in[2];
    const int*   stridep = (const int*)d_in[3];
    float* out = (float*)d_out;
    char* ws = (char*)d_ws;

    uint32_t* mkey  = (uint32_t*)(ws + OFF_MKEY);
    uint8_t*  cls   = (uint8_t*)(ws + OFF_CLS);
    uint32_t* hist1 = (uint32_t*)(ws + OFF_HIST1);
    uint32_t* hist2 = (uint32_t*)(ws + OFF_HIST2);
    uint32_t* scal  = (uint32_t*)(ws + OFF_SCAL);
    unsigned long long* grp = (unsigned long long*)(ws + OFF_GRP);
    uint32_t* zin   = (uint32_t*)(ws + OFF_ZIN);
    unsigned long long* cand = (unsigned long long*)(ws + OFF_CAND);
    uint64_t* mask  = (uint64_t*)(ws + OFF_MASK);

    k_score<<<dim3(NBLK_SCORE), dim3(256), 0, stream>>>(logits, mkey, cls, hist1, hist2, scal, zin);
    k_compact<<<dim3(256), dim3(256), 0, stream>>>(mkey, hist1, hist2, scal, cand);
    k_rank<<<dim3(64), dim3(256), 0, stream>>>(cand, scal, deltas, locs, stridep, cls, out);
    k_maskscan<<<dim3(500), dim3(256), 0, stream>>>(out, scal, mask, grp, zin, out);
}

// Round 8
// 87.360 us; speedup vs baseline: 2.1550x; 1.1207x over previous
//
#include <hip/hip_runtime.h>
#include <stdint.h>
#include <math.h>

#pragma clang fp contract(off)

#define N_ROWS 1048576
#define N_CLS  20
#define K_TOP  2000
#define CAND_MAX 4096
#define H_COPIES 4
#define MAGIC 0x5AD0C0DEu

// scal slots (dwords) -- all inside the zeroed region
#define SC_CNT   0
#define SC_MAXK  1
#define SC_DONE  2   // maskscan done-counter

// ws layout
static constexpr size_t OFF_MKEY  = 0;                             // u32[N]
static constexpr size_t OFF_CLS   = OFF_MKEY + 4ull * N_ROWS;      // u8[N]
static constexpr size_t OFF_HIST1 = OFF_CLS + (size_t)N_ROWS;      // u32[4*256] -- zero region start
static constexpr size_t OFF_HIST2 = OFF_HIST1 + 4096;              // u32[4*256]
static constexpr size_t OFF_SCAL  = OFF_HIST2 + 4096;              // u32[16]
static constexpr size_t OFF_GRP   = OFF_SCAL + 64;                 // u64[32]    -- zero region end (2128 dwords)
static constexpr size_t OFF_ZIN   = OFF_GRP + 256;                 // u32[8] MAGIC words (reset by last kernel)
static constexpr size_t OFF_CAND  = OFF_ZIN + 256;                 // u64[CAND_MAX]
static constexpr size_t OFF_MASK  = OFF_CAND + 8ull * CAND_MAX;    // u64[K_TOP*32]

__device__ __forceinline__ uint32_t mono_key(float f) {
    uint32_t u = __float_as_uint(f);
    return u ^ ((u & 0x80000000u) ? 0xFFFFFFFFu : 0x80000000u);
}
__device__ __forceinline__ float mono_inv(uint32_t k) {
    uint32_t u = (k & 0x80000000u) ? (k ^ 0x80000000u) : ~k;
    return __uint_as_float(u);
}

// ---- D1: per-row max/argmax of logits (LDS-staged coalesced loads) -> mkey, cls,
//      with fused stage-1 histogram. Zeroing handled in-kernel by blocks 0..7 via
//      the zin-MAGIC handshake (value-semantic, poison-proof). NO grid barrier:
//      1024 blocks, ~4/CU, full occupancy/ILP. Spin is deadlock-free by capacity
//      (22.5 KB LDS -> 7 blocks/CU co-residable >= 1024 total).
__global__ __launch_bounds__(256) void k_score(const float* __restrict__ logits,
                                               uint32_t* __restrict__ mkey,
                                               uint8_t* __restrict__ cls,
                                               uint32_t* __restrict__ hist1,   // zero region base
                                               uint32_t* __restrict__ zin) {
    __shared__ uint32_t stage[256 * 21];   // 256 rows x 20 words, padded to 21
    __shared__ uint32_t h1[256];
    int t = threadIdx.x, b = blockIdx.x;

    // zero phase: blocks 0..7 zero the 2128-dword region via device atomics,
    // then publish MAGIC.
    if (b < 8) {
        uint32_t zd = atomicExch(&hist1[b * 256 + t], 0u);
        if (b == 7 && t < 80) zd += atomicExch(&hist1[2048 + t], 0u);
        asm volatile("" :: "v"(zd));
        asm volatile("s_waitcnt vmcnt(0)" ::: "memory");
        __syncthreads();
        if (t == 0) atomicExch(&zin[b], MAGIC);
    }

    h1[t] = 0;
    __syncthreads();
    size_t rowbase0 = (size_t)b * 1024;
    for (int g = 0; g < 4; ++g) {
        const float4* src = (const float4*)(logits + (rowbase0 + (size_t)g * 256) * N_CLS);
#pragma unroll
        for (int q = 0; q < 5; ++q) {
            float4 v = src[q * 256 + t];            // fully coalesced 16B/lane
            int w0 = (q * 256 + t) * 4;
#pragma unroll
            for (int e = 0; e < 4; ++e) {
                int w = w0 + e;                     // stage addr = w + w/20  (row pad 20->21)
                stage[w + ((w * 52429u) >> 20)] = __float_as_uint((&v.x)[e]);
            }
        }
        __syncthreads();
        const uint32_t* row = &stage[t * 21];
        float m = __uint_as_float(row[0]); int ci = 0;
#pragma unroll
        for (int c = 1; c < 20; ++c) {
            float v = __uint_as_float(row[c]);
            if (v > m) { m = v; ci = c; }
        }
        size_t ri = rowbase0 + (size_t)g * 256 + t;
        uint32_t u = mono_key(m);
        mkey[ri] = u;
        cls[ri] = (uint8_t)ci;
        atomicAdd(&h1[u >> 24], 1u);
        __syncthreads();
    }

    // wait for zeroing (normally long done: zero ~1us << compute ~12us)
    for (;;) {
        int ok = 1;
        if (t < 8) ok = (atomicAdd(&zin[t], 0u) == MAGIC) ? 1 : 0;
        if (__syncthreads_count(ok) == 256) break;
        __builtin_amdgcn_s_sleep(16);
    }
    uint32_t hv = h1[t];
    if (hv) atomicAdd(&hist1[(b & 3) * 256 + t], hv);  // kernel-end drain handles visibility
}

// find8: suffix scan over summed hist1 -> (b0, R1). Runs redundantly per block
// (plain loads: cross-dispatch coherent).
__device__ __forceinline__ void find8(const uint32_t* __restrict__ hist1,
                                      uint32_t* sfx, uint32_t* pb0, uint32_t* pR1,
                                      uint32_t& b0, uint32_t& R1) {
    int t = threadIdx.x;
    uint32_t h = 0;
#pragma unroll
    for (int k = 0; k < H_COPIES; ++k) h += hist1[k * 256 + t];
    sfx[t] = h;
    __syncthreads();
    for (int off = 1; off < 256; off <<= 1) {
        uint32_t v = (t + off < 256) ? sfx[t + off] : 0;
        __syncthreads();
        sfx[t] += v;
        __syncthreads();
    }
    if (sfx[t] >= (uint32_t)K_TOP && (t == 255 || sfx[t + 1] < (uint32_t)K_TOP)) {
        *pb0 = (uint32_t)t;
        *pR1 = (uint32_t)K_TOP - (sfx[t] - h);
    }
    __syncthreads();
    b0 = *pb0; R1 = *pR1;
}

// ---- D2: restricted 8-bit stage-2 histogram (bits 23:16 where top byte == b0)
__global__ __launch_bounds__(256) void k_hist2(const uint32_t* __restrict__ mkey,
                                               const uint32_t* __restrict__ hist1,
                                               uint32_t* __restrict__ hist2) {
    __shared__ uint32_t sfx[256];
    __shared__ uint32_t h2[256];
    __shared__ uint32_t sb0, sR1;
    int t = threadIdx.x;
    h2[t] = 0;
    uint32_t b0, R1;
    find8(hist1, sfx, &sb0, &sR1, b0, R1);
    uint4 v = ((const uint4*)mkey)[(size_t)blockIdx.x * 256 + t];  // 1024 rows/block
    if ((v.x >> 24) == b0) atomicAdd(&h2[(v.x >> 16) & 0xFFu], 1u);
    if ((v.y >> 24) == b0) atomicAdd(&h2[(v.y >> 16) & 0xFFu], 1u);
    if ((v.z >> 24) == b0) atomicAdd(&h2[(v.z >> 16) & 0xFFu], 1u);
    if ((v.w >> 24) == b0) atomicAdd(&h2[(v.w >> 16) & 0xFFu], 1u);
    __syncthreads();
    uint32_t hv = h2[t];
    if (hv) atomicAdd(&hist2[(blockIdx.x & (H_COPIES - 1)) * 256 + t], hv);
}

// ---- D3: per-block redundant final find (find8 + stage-2 suffix scan -> T16-1),
//      then compact candidates ((mkey>>16) >= T), LDS-staged, 1 global atomic/block.
__global__ __launch_bounds__(256) void k_compact(const uint32_t* __restrict__ mkey,
                                                 const uint32_t* __restrict__ hist1,
                                                 const uint32_t* __restrict__ hist2,
                                                 uint32_t* __restrict__ scal,
                                                 unsigned long long* __restrict__ cand) {
    __shared__ uint32_t sfx[256];
    __shared__ uint32_t sb0, sR1, sT;
    __shared__ uint32_t cnt, gbase;
    __shared__ uint64_t stg[1024];
    int t = threadIdx.x;
    int lane = t & 63;
    if (t == 0) cnt = 0;
    uint32_t b0, R1;
    find8(hist1, sfx, &sb0, &sR1, b0, R1);
    // stage-2 suffix scan (reuse sfx)
    uint32_t h = 0;
#pragma unroll
    for (int k = 0; k < H_COPIES; ++k) h += hist2[k * 256 + t];
    __syncthreads();
    sfx[t] = h;
    __syncthreads();
    for (int off = 1; off < 256; off <<= 1) {
        uint32_t v = (t + off < 256) ? sfx[t + off] : 0;
        __syncthreads();
        sfx[t] += v;
        __syncthreads();
    }
    if (sfx[t] >= R1 && (t == 255 || sfx[t + 1] < R1)) {
        uint32_t t16 = (b0 << 8) | (uint32_t)t;
        sT = (t16 > 0) ? (t16 - 1) : 0;            // -1 bin safety: rounded-sigmoid ties
    }
    __syncthreads();
    uint32_t T = sT;
    const uint4* m4 = (const uint4*)mkey;
    size_t base = (size_t)blockIdx.x * 1024;       // uint4 index; 4096 rows/block
    for (int it = 0; it < 4; ++it) {
        uint32_t r0 = (uint32_t)((base + it * 256 + t) * 4);
        uint4 v = m4[base + it * 256 + t];
#pragma unroll
        for (int e = 0; e < 4; ++e) {
            uint32_t u = (e == 0) ? v.x : (e == 1) ? v.y : (e == 2) ? v.z : v.w;
            bool pass = (u >> 16) >= T;
            unsigned long long bal = __ballot(pass);
            if (bal) {
                uint32_t wbase = 0;
                if (lane == 0) wbase = atomicAdd(&cnt, (uint32_t)__popcll(bal));
                wbase = __shfl(wbase, 0);
                if (pass) {
                    uint32_t pos = wbase + (uint32_t)__popcll(bal & ((1ull << lane) - 1ull));
                    if (pos < 1024) stg[pos] = ((uint64_t)u << 32) | (r0 + e);
                }
            }
        }
    }
    __syncthreads();
    uint32_t n = cnt; if (n > 1024) n = 1024;
    if (t == 0 && n) gbase = atomicAdd(&scal[SC_CNT], n);
    __syncthreads();
    if (n) {
        uint32_t gb = gbase;
        for (uint32_t i = t; i < n; i += 256) {
            uint32_t pos = gb + i;
            if (pos < (uint32_t)CAND_MAX) cand[pos] = stg[i];
        }
    }
}

// ---- D4: rank-by-counting, j-PARALLEL: wave-per-candidate, lanes split the scan,
//      shuffle-reduce (proven R7).
__global__ __launch_bounds__(256) void k_rank(const unsigned long long* __restrict__ cand,
                                              uint32_t* __restrict__ scal,
                                              const float* __restrict__ deltas,
                                              const float* __restrict__ locs,
                                              const int* __restrict__ stridep,
                                              const uint8_t* __restrict__ cls,
                                              float* __restrict__ out) {
    __shared__ uint64_t keys[CAND_MAX];
    int t = threadIdx.x;
    uint32_t M = scal[SC_CNT];
    if (M > (uint32_t)CAND_MAX) M = CAND_MAX;
    for (uint32_t i = t; i < M; i += 256) {
        unsigned long long cd = cand[i];
        uint32_t mk = (uint32_t)(cd >> 32);
        uint32_t row = (uint32_t)cd & (N_ROWS - 1);
        float m = mono_inv(mk);
        float ef = (float)exp(-(double)m);          // ~correctly-rounded fp32 expf
        float s = 1.0f / (1.0f + ef);
        keys[i] = ((uint64_t)(~__float_as_uint(s)) << 32) | row;
    }
    __syncthreads();
    int wid = t >> 6, lane = t & 63;
    float stridef = (float)(*stridep);
    float wmx = -3.4e38f;
    for (uint32_t c = (uint32_t)blockIdx.x * 4 + wid; c < M; c += 256) {  // 64 blocks * 4 waves
        uint64_t myk = keys[c];
        uint32_t r = 0;
        for (uint32_t j = lane; j < M; j += 64) r += (keys[j] < myk) ? 1u : 0u;
#pragma unroll
        for (int o = 32; o > 0; o >>= 1) r += __shfl_down(r, o);
        if (lane == 0 && r < (uint32_t)K_TOP) {
            uint32_t row = (uint32_t)myk & (N_ROWS - 1);
            float s = __uint_as_float(~(uint32_t)(myk >> 32));
            float4 dl = ((const float4*)deltas)[row];
            float2 lc = ((const float2*)locs)[row];
            float d0 = dl.x * stridef, d1 = dl.y * stridef, d2 = dl.z * stridef, d3 = dl.w * stridef;
            float b0f = lc.x - d0, b1f = lc.y - d1, b2f = lc.x + d2, b3f = lc.y + d3;
            float4 bx = { b0f, b1f, b2f, b3f };
            *(float4*)&out[4 * r] = bx;
            out[8000 + r] = s;
            out[10000 + r] = (float)cls[row];
            wmx = fmaxf(wmx, fmaxf(fmaxf(b0f, b1f), fmaxf(b2f, b3f)));
        }
    }
    if (lane == 0) atomicMax(&scal[SC_MAXK], mono_key(wmx));
}

// ---- D5: pairwise suppression mask (quirky IoU replicated exactly) + fused scan.
//      Atomic-only cross-block handoff (proven R5/R7). Tail: reset zin MAGIC words.
__global__ __launch_bounds__(256) void k_maskscan(const float* __restrict__ out_ro,
                                                  uint32_t* __restrict__ scal,
                                                  uint64_t* __restrict__ mask,
                                                  unsigned long long* __restrict__ grp,
                                                  uint32_t* __restrict__ zin,
                                                  float* __restrict__ out) {
    __shared__ int lastdone;
    int t = threadIdx.x;
    int lane = t & 63;
    int i = blockIdx.x * 4 + (t >> 6);              // 2000 waves total
    float off1 = mono_inv(scal[SC_MAXK]) + 1.0f;    // max_coord + 1 (prev dispatch, coherent)
    float4 boxi = *(const float4*)&out_ro[4 * i];
    float oi = out_ro[10000 + i] * off1;
    float x1i = boxi.x + oi, y2i = boxi.y + oi, x2i = boxi.z + oi, y1i = boxi.w + oi;
    float ai = (x2i - x1i) * (y2i - y1i);
    unsigned long long dummy = 0;
    for (int jb = 0; jb < 32; ++jb) {
        int j = jb * 64 + lane;
        bool sup = false;
        if (j < K_TOP && j > i) {
            float4 boxj = *(const float4*)&out_ro[4 * j];
            float oj = out_ro[10000 + j] * off1;
            float x1j = boxj.x + oj, y2j = boxj.y + oj, x2j = boxj.z + oj, y1j = boxj.w + oj;
            float aj = (x2j - x1j) * (y2j - y1j);
            float xx1 = fmaxf(x1i, x1j);
            float yy1 = fminf(y1i, y1j);
            float xx2 = fminf(x2i, x2j);
            float yy2 = fmaxf(y2i, y2j);
            float inter = fabsf(xx2 - xx1) * fabsf(yy2 - yy1);
            float iou = inter / ((ai + aj) - inter);
            sup = iou > 0.5f;
        }
        unsigned long long bits = __ballot(sup);
        if (lane == 0) {
            dummy += atomicExch(&mask[(size_t)i * 32 + jb], bits);
            if (bits) dummy += atomicOr(&grp[i >> 6], 1ull << (i & 63));
        }
    }
    asm volatile("" :: "v"(dummy));                 // force atomic returns (vmcnt drained)
    asm volatile("s_waitcnt vmcnt(0) lgkmcnt(0)" ::: "memory");
    __syncthreads();
    if (t == 0) {
        unsigned old = atomicAdd(&scal[SC_DONE], 1u);
        lastdone = (old == (unsigned)(gridDim.x - 1)) ? 1 : 0;
    }
    __syncthreads();
    if (!lastdone) return;

    if (t < 64) {
        int l = t;                                  // lane w<32 holds active word w
        uint64_t g = (l < 32) ? atomicOr(&grp[l], 0ull) : 0ull;
        uint64_t active = ~0ull;
        if (__ballot(g != 0ull)) {
            for (int gg = 0; gg < 32; ++gg) {
                uint64_t nz = __shfl(g, gg);
                while (nz) {
                    int b = __ffsll((long long)nz) - 1;
                    nz &= nz - 1;
                    int ii = gg * 64 + b;
                    uint64_t aw = __shfl(active, gg);
                    bool kept = (aw >> b) & 1ull;
                    uint64_t m = (l < 32) ? atomicOr(&mask[(size_t)ii * 32 + l], 0ull) : 0ull;
                    if (kept) active &= ~m;
                }
            }
        }
        if (l < 32) {
            int limit = K_TOP - l * 64;
            int nvec = limit < 64 ? limit / 4 : 16;
            for (int v = 0; v < nvec; ++v) {
                float4 f;
                f.x = ((active >> (4 * v + 0)) & 1ull) ? 1.0f : 0.0f;
                f.y = ((active >> (4 * v + 1)) & 1ull) ? 1.0f : 0.0f;
                f.z = ((active >> (4 * v + 2)) & 1ull) ? 1.0f : 0.0f;
                f.w = ((active >> (4 * v + 3)) & 1ull) ? 1.0f : 0.0f;
                *(float4*)&out[12000 + l * 64 + 4 * v] = f;
            }
        }
    }
    // reset MAGIC words for the next replay (zeroed state is what D1 expects)
    if (t < 8) atomicExch(&zin[t], 0u);
}

extern "C" void kernel_launch(void* const* d_in, const int* in_sizes, int n_in,
                              void* d_out, int out_size, void* d_ws, size_t ws_size,
                              hipStream_t stream) {
    const float* deltas = (const float*)d_in[0];
    const float* locs   = (const float*)d_in[1];
    const float* logits = (const float*)d_in[2];
    const int*   stridep = (const int*)d_in[3];
    float* out = (float*)d_out;
    char* ws = (char*)d_ws;

    uint32_t* mkey  = (uint32_t*)(ws + OFF_MKEY);
    uint8_t*  cls   = (uint8_t*)(ws + OFF_CLS);
    uint32_t* hist1 = (uint32_t*)(ws + OFF_HIST1);
    uint32_t* hist2 = (uint32_t*)(ws + OFF_HIST2);
    uint32_t* scal  = (uint32_t*)(ws + OFF_SCAL);
    unsigned long long* grp = (unsigned long long*)(ws + OFF_GRP);
    uint32_t* zin   = (uint32_t*)(ws + OFF_ZIN);
    unsigned long long* cand = (unsigned long long*)(ws + OFF_CAND);
    uint64_t* mask  = (uint64_t*)(ws + OFF_MASK);

    k_score<<<dim3(1024), dim3(256), 0, stream>>>(logits, mkey, cls, hist1, zin);
    k_hist2<<<dim3(1024), dim3(256), 0, stream>>>(mkey, hist1, hist2);
    k_compact<<<dim3(256), dim3(256), 0, stream>>>(mkey, hist1, hist2, scal, cand);
    k_rank<<<dim3(64), dim3(256), 0, stream>>>(cand, scal, deltas, locs, stridep, cls, out);
    k_maskscan<<<dim3(500), dim3(256), 0, stream>>>(out, scal, mask, grp, zin, out);
}